// Round 8
// baseline (255.624 us; speedup 1.0000x reference)
//
#include <hip/hip_runtime.h>

// DenseGrid multi-LOD bilinear — binned pipeline v6 (L1-resident bins).
// R2: monolithic 340us (L2-miss bound). R3: nt scattered 16B stores bad.
// R4: full-line writes, binned 167us. R5: LDS tiles null. R6: atomic-free
// sort (pre 35us) but 4B recs -> scattered x reads. R7: SoA recs, FETCH
// 69.5MB, binned still 185us -> NOT traffic-bound; ~20 scattered L2-line
// touches/point is the wall (per-bin tiles 25KB x 3-8 blocks >> 32KB L1).
// R8: 128x128 bins (tile set ~6.3KB/bin) + 40KB LDS pad caps 4 blocks/CU
//     (= 32 waves, full occupancy; 4 x 6.3KB fits 32KB L1) -> gathers become
//     L1 hits. Cached stores (TCP write-through: stores don't thrash L1).
//     u16 counts (PPB=16384), ws ~28.2MB, still zero global atomics.

typedef float    fx4 __attribute__((ext_vector_type(4)));
typedef float    fx2 __attribute__((ext_vector_type(2)));
typedef unsigned ux4 __attribute__((ext_vector_type(4)));

#define NBDIM 128
#define NBINS (NBDIM * NBDIM)      // 16384
#define PPB   16384                // points per sort block (fits u16 counts)

__device__ __forceinline__ int bin_of(float px, float py) {
    int bx = min(max((int)(px * (float)NBDIM), 0), NBDIM - 1);
    int by = min(max((int)(py * (float)NBDIM), 0), NBDIM - 1);
    return by * NBDIM + bx;
}

__device__ __forceinline__ fx4 bilerp_one(const float* __restrict__ g, int res,
                                          float px, float py) {
    float rm1 = (float)(res - 1);
    float fx = px * rm1, fy = py * rm1;
    float cmax = rm1 - 1e-5f;
    float xc = fminf(fmaxf(fx, 0.0f), cmax);
    float yc = fminf(fmaxf(fy, 0.0f), cmax);
    int x1 = (int)xc, y1 = (int)yc;              // >=0 -> trunc == floor
    int x2 = min(x1 + 1, res - 1), y2 = min(y1 + 1, res - 1);
    float x1f = (float)x1, y1f = (float)y1, x2f = (float)x2, y2f = (float)y2;
    float w1 = (x2f - fx) * (y2f - fy);
    float w2 = (fx - x1f) * (y2f - fy);
    float w3 = (x2f - fx) * (fy - y1f);
    float w4 = (fx - x1f) * (fy - y1f);
    const fx4* gc = (const fx4*)g;
    fx4 v1 = gc[x1 + y1 * res];
    fx4 v2 = gc[x2 + y1 * res];
    fx4 v3 = gc[x1 + y2 * res];
    fx4 v4 = gc[x2 + y2 * res];
    return w1 * v1 + w2 * v2 + w3 * v3 + w4 * v4;
}

// ---- P1: per-block LDS histogram -> cnt[bin*nblk + blk] (u16) ---------------
__global__ __launch_bounds__(1024) void hist2_kernel(const float* __restrict__ x,
                                                     unsigned short* __restrict__ cnt,
                                                     int npts, int nblk) {
    __shared__ unsigned h[NBINS];                 // 64 KB
    int t = threadIdx.x, blk = blockIdx.x;
    for (int i = t; i < NBINS; i += 1024) h[i] = 0;
    __syncthreads();
    size_t base = (size_t)blk * PPB;
    #pragma unroll
    for (int j = 0; j < 8; ++j) {
        size_t n = base + (size_t)j * 2048 + (size_t)t * 2;  // 2 pts/thread/iter
        if (n < (size_t)npts) {
            if (n + 1 < (size_t)npts) {
                fx4 q = *(const fx4*)(x + 2 * n);
                atomicAdd(&h[bin_of(q.x, q.y)], 1u);
                atomicAdd(&h[bin_of(q.z, q.w)], 1u);
            } else {
                fx2 q = *(const fx2*)(x + 2 * n);
                atomicAdd(&h[bin_of(q.x, q.y)], 1u);
            }
        }
    }
    __syncthreads();
    for (int i = t; i < NBINS; i += 1024)
        cnt[(size_t)i * nblk + blk] = (unsigned short)h[i];
}

// ---- P2: per-bin totals (one wave per bin row) ------------------------------
__global__ __launch_bounds__(256) void rowsum_kernel(const unsigned short* __restrict__ cnt,
                                                     unsigned* __restrict__ T,
                                                     int nblk) {
    int wave = (blockIdx.x * 256 + threadIdx.x) >> 6;
    int lane = threadIdx.x & 63;
    if (wave >= NBINS) return;
    const unsigned short* row = cnt + (size_t)wave * nblk;
    unsigned sum = 0;
    for (int c = lane; c < nblk; c += 64) sum += row[c];
    #pragma unroll
    for (int d = 32; d; d >>= 1) sum += __shfl_down(sum, d, 64);
    if (lane == 0) T[wave] = sum;
}

// ---- P3: exclusive scan of 16384 bin totals (single block, 16/thread) -------
__global__ __launch_bounds__(1024) void scanT_kernel(const unsigned* __restrict__ T,
                                                     unsigned* __restrict__ binStart,
                                                     int npts) {
    __shared__ unsigned s[1024];
    int t = threadIdx.x;
    unsigned h[16];
    #pragma unroll
    for (int j = 0; j < 4; ++j) {
        ux4 v = ((const ux4*)T)[t * 4 + j];
        h[4 * j + 0] = v.x; h[4 * j + 1] = v.y;
        h[4 * j + 2] = v.z; h[4 * j + 3] = v.w;
    }
    unsigned seg = 0;
    #pragma unroll
    for (int j = 0; j < 16; ++j) seg += h[j];
    s[t] = seg;
    __syncthreads();
    for (int off = 1; off < 1024; off <<= 1) {    // Hillis-Steele inclusive
        unsigned v = (t >= off) ? s[t - off] : 0u;
        __syncthreads();
        s[t] += v;
        __syncthreads();
    }
    unsigned run = t ? s[t - 1] : 0u;
    #pragma unroll
    for (int j = 0; j < 16; ++j) {
        binStart[t * 16 + j] = run;
        run += h[j];
    }
    if (t == 1023) binStart[NBINS] = (unsigned)npts;
}

// ---- P4: per-bin row exclusive scan of u16 counts, IN PLACE (local base 0) --
__global__ __launch_bounds__(256) void rowscan_kernel(unsigned short* __restrict__ cnt,
                                                      int nblk) {
    int wave = (blockIdx.x * 256 + threadIdx.x) >> 6;
    int lane = threadIdx.x & 63;
    if (wave >= NBINS) return;
    unsigned short* row = cnt + (size_t)wave * nblk;
    unsigned running = 0;
    for (int c0 = 0; c0 < nblk; c0 += 64) {
        int c = c0 + lane;
        unsigned v = (c < nblk) ? (unsigned)row[c] : 0u;
        unsigned orig = v;
        #pragma unroll
        for (int d = 1; d < 64; d <<= 1) {
            unsigned y = __shfl_up(v, d, 64);
            if (lane >= d) v += y;
        }
        if (c < nblk) row[c] = (unsigned short)(running + v - orig);
        running += __shfl(v, 63, 64);
    }
}

// ---- P5: scatter SoA records (LDS offsets = binStart + local rank) ----------
__global__ __launch_bounds__(1024) void scatter2_kernel(const float* __restrict__ x,
                                                        const unsigned short* __restrict__ cnt,
                                                        const unsigned* __restrict__ binStart,
                                                        fx2* __restrict__ recXY,
                                                        unsigned* __restrict__ recN,
                                                        int npts, int nblk) {
    __shared__ unsigned off[NBINS];               // 64 KB
    int t = threadIdx.x, blk = blockIdx.x;
    for (int i = t; i < NBINS; i += 1024)
        off[i] = binStart[i] + (unsigned)cnt[(size_t)i * nblk + blk];
    __syncthreads();
    size_t base = (size_t)blk * PPB;
    #pragma unroll
    for (int j = 0; j < 8; ++j) {
        size_t n = base + (size_t)j * 2048 + (size_t)t * 2;
        if (n < (size_t)npts) {
            if (n + 1 < (size_t)npts) {
                fx4 q = *(const fx4*)(x + 2 * n);
                unsigned s0 = atomicAdd(&off[bin_of(q.x, q.y)], 1u);
                unsigned s1 = atomicAdd(&off[bin_of(q.z, q.w)], 1u);
                fx2 a; a.x = q.x; a.y = q.y;
                fx2 b2; b2.x = q.z; b2.y = q.w;
                recXY[s0] = a;  recN[s0] = (unsigned)n;
                recXY[s1] = b2; recN[s1] = (unsigned)(n + 1);
            } else {
                fx2 q = *(const fx2*)(x + 2 * n);
                unsigned s0 = atomicAdd(&off[bin_of(q.x, q.y)], 1u);
                recXY[s0] = q; recN[s0] = (unsigned)n;
            }
        }
    }
}

// ---- P6: binned main pass — 8 lanes per point; 4 blocks/CU -> L1-fit tiles --
__global__ __launch_bounds__(512) void binned_kernel(
    const fx2* __restrict__ recXY, const unsigned* __restrict__ recN,
    const unsigned* __restrict__ binStart,
    const float* __restrict__ g0, const float* __restrict__ g1,
    const float* __restrict__ g2, const float* __restrict__ g3,
    const float* __restrict__ g4, const float* __restrict__ g5,
    const float* __restrict__ g6, const float* __restrict__ g7,
    float* __restrict__ out) {
    // 40KB LDS pad: 160/40 = 4 blocks/CU (= 32 waves, full occupancy).
    // 4 bins x ~6.3KB high-LOD tile footprint fits the 32KB L1.
    __shared__ unsigned pad[10240];
    // XCD swizzle: 16384 % 8 == 0 -> each XCD gets a contiguous bin band.
    int b = (blockIdx.x & 7) * (NBINS / 8) + (blockIdx.x >> 3);
    if (threadIdx.x == 0) {                        // real use keeps pad allocated
        pad[0] = binStart[b];
        pad[1] = binStart[b + 1];
    }
    __syncthreads();
    unsigned s = pad[0], e = pad[1];
    int lod = threadIdx.x & 7;
    const float* g =
        (lod < 4) ? ((lod < 2) ? ((lod == 0) ? g0 : g1)
                               : ((lod == 2) ? g2 : g3))
                  : ((lod < 6) ? ((lod == 4) ? g4 : g5)
                               : ((lod == 6) ? g6 : g7));
    int res = 16 << lod;
    unsigned i = s + (threadIdx.x >> 3);
    for (; i + 64 < e; i += 128) {                 // unroll-2 independent chains
        fx2 pa = __builtin_nontemporal_load(&recXY[i]);
        unsigned na = __builtin_nontemporal_load(&recN[i]);
        fx2 pb = __builtin_nontemporal_load(&recXY[i + 64]);
        unsigned nb = __builtin_nontemporal_load(&recN[i + 64]);
        fx4 oa = bilerp_one(g, res, pa.x, pa.y);
        fx4 ob = bilerp_one(g, res, pb.x, pb.y);
        ((fx4*)out)[(size_t)na * 8 + lod] = oa;    // cached: full-line merge in L2
        ((fx4*)out)[(size_t)nb * 8 + lod] = ob;
    }
    for (; i < e; i += 64) {
        fx2 p = __builtin_nontemporal_load(&recXY[i]);
        unsigned n = __builtin_nontemporal_load(&recN[i]);
        fx4 o = bilerp_one(g, res, p.x, p.y);
        ((fx4*)out)[(size_t)n * 8 + lod] = o;
    }
}

// ---- Fallback: proven round-2 monolithic kernel -----------------------------
__global__ __launch_bounds__(256) void densegrid_kernel(
    const float* __restrict__ xin,
    const float* __restrict__ g0, const float* __restrict__ g1,
    const float* __restrict__ g2, const float* __restrict__ g3,
    const float* __restrict__ g4, const float* __restrict__ g5,
    const float* __restrict__ g6, const float* __restrict__ g7,
    float* __restrict__ out, int npts) {
    int tid = blockIdx.x * blockDim.x + threadIdx.x;
    int n = tid >> 3;
    if (n >= npts) return;
    int lod = tid & 7;
    const float* g =
        (lod < 4) ? ((lod < 2) ? ((lod == 0) ? g0 : g1)
                               : ((lod == 2) ? g2 : g3))
                  : ((lod < 6) ? ((lod == 4) ? g4 : g5)
                               : ((lod == 6) ? g6 : g7));
    int res = 16 << lod;
    fx2 p = *(const fx2*)(xin + (size_t)n * 2);
    fx4 o = bilerp_one(g, res, p.x, p.y);
    __builtin_nontemporal_store(o, (fx4*)out + (size_t)n * 8 + lod);
}

extern "C" void kernel_launch(void* const* d_in, const int* in_sizes, int n_in,
                              void* d_out, int out_size, void* d_ws, size_t ws_size,
                              hipStream_t stream) {
    const float* x  = (const float*)d_in[0];
    const float* g0 = (const float*)d_in[1];
    const float* g1 = (const float*)d_in[2];
    const float* g2 = (const float*)d_in[3];
    const float* g3 = (const float*)d_in[4];
    const float* g4 = (const float*)d_in[5];
    const float* g5 = (const float*)d_in[6];
    const float* g6 = (const float*)d_in[7];
    const float* g7 = (const float*)d_in[8];
    float* out = (float*)d_out;
    int npts = in_sizes[0] / 2;

    int nblk = (npts + PPB - 1) / PPB;            // 123 for 2M points
    size_t mat  = (((size_t)NBINS * nblk * 2) + 255) & ~(size_t)255;  // u16 counts
    size_t o_T  = mat;
    size_t o_bs = o_T + (((size_t)NBINS * 4 + 255) & ~(size_t)255);
    size_t o_xy = o_bs + ((((size_t)NBINS + 1) * 4 + 255) & ~(size_t)255);
    size_t o_n  = o_xy + (size_t)npts * 8;
    size_t need = o_n + (size_t)npts * 4;         // ~28.2 MB @ 2M pts

    if (ws_size >= need && npts <= PPB * 65535) {
        unsigned short* cnt = (unsigned short*)d_ws;   // local-exclusive after rowscan
        unsigned* T         = (unsigned*)((char*)d_ws + o_T);
        unsigned* binStart  = (unsigned*)((char*)d_ws + o_bs);
        fx2*      recXY     = (fx2*)((char*)d_ws + o_xy);
        unsigned* recN      = (unsigned*)((char*)d_ws + o_n);

        hist2_kernel<<<nblk, 1024, 0, stream>>>(x, cnt, npts, nblk);
        rowsum_kernel<<<(NBINS * 64) / 256, 256, 0, stream>>>(cnt, T, nblk);
        scanT_kernel<<<1, 1024, 0, stream>>>(T, binStart, npts);
        rowscan_kernel<<<(NBINS * 64) / 256, 256, 0, stream>>>(cnt, nblk);
        scatter2_kernel<<<nblk, 1024, 0, stream>>>(x, cnt, binStart, recXY, recN,
                                                   npts, nblk);
        binned_kernel<<<NBINS, 512, 0, stream>>>(recXY, recN, binStart,
                                                 g0, g1, g2, g3, g4, g5, g6, g7,
                                                 out);
    } else {
        int total = npts * 8;
        densegrid_kernel<<<(total + 255) / 256, 256, 0, stream>>>(
            x, g0, g1, g2, g3, g4, g5, g6, g7, out, npts);
    }
}

// Round 9
// 231.235 us; speedup vs baseline: 1.1055x; 1.1055x over previous
//
#include <hip/hip_runtime.h>

// DenseGrid multi-LOD bilinear — binned pipeline v7.
// R2: monolithic 340us (L2-miss/MSHR-latency bound, FETCH 873MB; LLC thrashed
//     by the 250MB write stream so grids never stay resident).
// R4: bin-order + full-line cached writes: binned 167us.
// R6/R7: atomic-free counting sort at 4096 bins = ~39us pre-pass (proven).
// R8: 16384 bins -> binned 155us (tiles L1-fit) but sort pre-passes ~100us
//     (64KB LDS hist, 123-block grid < 1/CU). LDS pad was compiler-shrunk.
// R9: 4096-bin sort (verbatim R7, ~39us) + IN-BLOCK quadrant sub-sort in the
//     binned kernel (LDS counting sort into 2x2 = the 128x128 sub-bins) ->
//     instantaneous tile footprint ~6.4KB/block, 4 blocks/CU -> L1-fit, with
//     coalesced record loads. Writes: cached full-line (8 lanes/point).

typedef float    fx4 __attribute__((ext_vector_type(4)));
typedef float    fx2 __attribute__((ext_vector_type(2)));
typedef unsigned ux4 __attribute__((ext_vector_type(4)));

#define NBDIM 64
#define NBINS (NBDIM * NBDIM)
#define PPB   8192              // points per sort block

__device__ __forceinline__ int bin_of(float px, float py) {
    int bx = min(max((int)(px * (float)NBDIM), 0), NBDIM - 1);
    int by = min(max((int)(py * (float)NBDIM), 0), NBDIM - 1);
    return by * NBDIM + bx;
}

__device__ __forceinline__ int quad_of(float px, float py) {
    int qx = min(max((int)(px * 128.0f), 0), 127) & 1;
    int qy = min(max((int)(py * 128.0f), 0), 127) & 1;
    return qy * 2 + qx;
}

__device__ __forceinline__ fx4 bilerp_one(const float* __restrict__ g, int res,
                                          float px, float py) {
    float rm1 = (float)(res - 1);
    float fx = px * rm1, fy = py * rm1;
    float cmax = rm1 - 1e-5f;
    float xc = fminf(fmaxf(fx, 0.0f), cmax);
    float yc = fminf(fmaxf(fy, 0.0f), cmax);
    int x1 = (int)xc, y1 = (int)yc;              // >=0 -> trunc == floor
    int x2 = min(x1 + 1, res - 1), y2 = min(y1 + 1, res - 1);
    float x1f = (float)x1, y1f = (float)y1, x2f = (float)x2, y2f = (float)y2;
    float w1 = (x2f - fx) * (y2f - fy);
    float w2 = (fx - x1f) * (y2f - fy);
    float w3 = (x2f - fx) * (fy - y1f);
    float w4 = (fx - x1f) * (fy - y1f);
    const fx4* gc = (const fx4*)g;
    fx4 v1 = gc[x1 + y1 * res];
    fx4 v2 = gc[x2 + y1 * res];
    fx4 v3 = gc[x1 + y2 * res];
    fx4 v4 = gc[x2 + y2 * res];
    return w1 * v1 + w2 * v2 + w3 * v3 + w4 * v4;
}

// ---- P1: per-block LDS histogram -> cnt[bin*nblk + blk] ---------------------
__global__ __launch_bounds__(1024) void hist2_kernel(const float* __restrict__ x,
                                                     unsigned* __restrict__ cnt,
                                                     int npts, int nblk) {
    __shared__ unsigned h[NBINS];                 // 16 KB
    int t = threadIdx.x, blk = blockIdx.x;
    for (int i = t; i < NBINS; i += 1024) h[i] = 0;
    __syncthreads();
    size_t base = (size_t)blk * PPB;
    #pragma unroll
    for (int j = 0; j < 4; ++j) {
        size_t n = base + (size_t)j * 2048 + (size_t)t * 2;  // 2 pts/thread/iter
        if (n < (size_t)npts) {
            if (n + 1 < (size_t)npts) {
                fx4 q = *(const fx4*)(x + 2 * n);
                atomicAdd(&h[bin_of(q.x, q.y)], 1u);
                atomicAdd(&h[bin_of(q.z, q.w)], 1u);
            } else {
                fx2 q = *(const fx2*)(x + 2 * n);
                atomicAdd(&h[bin_of(q.x, q.y)], 1u);
            }
        }
    }
    __syncthreads();
    for (int i = t; i < NBINS; i += 1024)
        cnt[(size_t)i * nblk + blk] = h[i];
}

// ---- P2: per-bin totals (one wave per bin row) ------------------------------
__global__ __launch_bounds__(256) void rowsum_kernel(const unsigned* __restrict__ cnt,
                                                     unsigned* __restrict__ T,
                                                     int nblk) {
    int wave = (blockIdx.x * 256 + threadIdx.x) >> 6;
    int lane = threadIdx.x & 63;
    if (wave >= NBINS) return;
    const unsigned* row = cnt + (size_t)wave * nblk;
    unsigned sum = 0;
    for (int c = lane; c < nblk; c += 64) sum += row[c];
    #pragma unroll
    for (int d = 32; d; d >>= 1) sum += __shfl_down(sum, d, 64);
    if (lane == 0) T[wave] = sum;
}

// ---- P3: exclusive scan of 4096 bin totals (single block) -------------------
__global__ __launch_bounds__(1024) void scanT_kernel(const unsigned* __restrict__ T,
                                                     unsigned* __restrict__ binStart,
                                                     int npts) {
    __shared__ unsigned s[1024];
    int t = threadIdx.x;
    ux4 h = ((const ux4*)T)[t];
    unsigned seg = h.x + h.y + h.z + h.w;
    s[t] = seg;
    __syncthreads();
    for (int off = 1; off < 1024; off <<= 1) {    // Hillis-Steele inclusive
        unsigned v = (t >= off) ? s[t - off] : 0u;
        __syncthreads();
        s[t] += v;
        __syncthreads();
    }
    unsigned run = t ? s[t - 1] : 0u;
    binStart[4 * t + 0] = run; run += h.x;
    binStart[4 * t + 1] = run; run += h.y;
    binStart[4 * t + 2] = run; run += h.z;
    binStart[4 * t + 3] = run;
    if (t == 1023) binStart[NBINS] = (unsigned)npts;
}

// ---- P4: per-bin row exclusive scan, IN PLACE (cnt becomes abs offsets) -----
__global__ __launch_bounds__(256) void rowscan_kernel(unsigned* __restrict__ cnt,
                                                      const unsigned* __restrict__ binStart,
                                                      int nblk) {
    int wave = (blockIdx.x * 256 + threadIdx.x) >> 6;
    int lane = threadIdx.x & 63;
    if (wave >= NBINS) return;
    unsigned* row = cnt + (size_t)wave * nblk;
    unsigned running = binStart[wave];
    for (int c0 = 0; c0 < nblk; c0 += 64) {
        int c = c0 + lane;
        unsigned v = (c < nblk) ? row[c] : 0u;
        unsigned orig = v;
        #pragma unroll
        for (int d = 1; d < 64; d <<= 1) {
            unsigned y = __shfl_up(v, d, 64);
            if (lane >= d) v += y;
        }
        if (c < nblk) row[c] = running + v - orig;    // exclusive + base
        running += __shfl(v, 63, 64);
    }
}

// ---- P5: scatter SoA records (LDS-local ranks, no global atomics) -----------
__global__ __launch_bounds__(1024) void scatter2_kernel(const float* __restrict__ x,
                                                        const unsigned* __restrict__ offs,
                                                        fx2* __restrict__ recXY,
                                                        unsigned* __restrict__ recN,
                                                        int npts, int nblk) {
    __shared__ unsigned off[NBINS];               // 16 KB
    int t = threadIdx.x, blk = blockIdx.x;
    for (int i = t; i < NBINS; i += 1024)
        off[i] = offs[(size_t)i * nblk + blk];
    __syncthreads();
    size_t base = (size_t)blk * PPB;
    #pragma unroll
    for (int j = 0; j < 4; ++j) {
        size_t n = base + (size_t)j * 2048 + (size_t)t * 2;
        if (n < (size_t)npts) {
            if (n + 1 < (size_t)npts) {
                fx4 q = *(const fx4*)(x + 2 * n);
                unsigned s0 = atomicAdd(&off[bin_of(q.x, q.y)], 1u);
                unsigned s1 = atomicAdd(&off[bin_of(q.z, q.w)], 1u);
                fx2 a; a.x = q.x; a.y = q.y;
                fx2 b2; b2.x = q.z; b2.y = q.w;
                recXY[s0] = a;  recN[s0] = (unsigned)n;
                recXY[s1] = b2; recN[s1] = (unsigned)(n + 1);
            } else {
                fx2 q = *(const fx2*)(x + 2 * n);
                unsigned s0 = atomicAdd(&off[bin_of(q.x, q.y)], 1u);
                recXY[s0] = q; recN[s0] = (unsigned)n;
            }
        }
    }
}

// ---- P6: binned main pass — in-block quadrant sort, 8 lanes per point -------
#define CHUNK 1024
__global__ __launch_bounds__(512) void binned_kernel(
    const fx2* __restrict__ recXY, const unsigned* __restrict__ recN,
    const unsigned* __restrict__ binStart,
    const float* __restrict__ g0, const float* __restrict__ g1,
    const float* __restrict__ g2, const float* __restrict__ g3,
    const float* __restrict__ g4, const float* __restrict__ g5,
    const float* __restrict__ g6, const float* __restrict__ g7,
    float* __restrict__ out) {
    __shared__ fx2 sxy[CHUNK];                    // 8 KB
    __shared__ unsigned snn[CHUNK];               // 4 KB
    __shared__ unsigned short sord[CHUNK];        // 2 KB
    __shared__ unsigned qoff[4];
    // XCD swizzle: 4096 bins % 8 == 0 -> each XCD gets 512 consecutive bins.
    int b = (blockIdx.x & 7) * (NBINS / 8) + (blockIdx.x >> 3);
    unsigned s = binStart[b], e = binStart[b + 1];
    int tid = threadIdx.x;
    int lod = tid & 7;
    const float* g =
        (lod < 4) ? ((lod < 2) ? ((lod == 0) ? g0 : g1)
                               : ((lod == 2) ? g2 : g3))
                  : ((lod < 6) ? ((lod == 4) ? g4 : g5)
                               : ((lod == 6) ? g6 : g7));
    int res = 16 << lod;

    for (unsigned c0 = s; c0 < e; c0 += CHUNK) {
        int m = (int)min((unsigned)CHUNK, e - c0);
        // coalesced stage of records
        for (int i = tid; i < m; i += 512) {
            sxy[i] = recXY[c0 + i];
            snn[i] = recN[c0 + i];
        }
        if (tid < 4) qoff[tid] = 0;
        __syncthreads();
        // count quadrants (LDS atomics, CU-local)
        for (int i = tid; i < m; i += 512) {
            fx2 p = sxy[i];
            atomicAdd(&qoff[quad_of(p.x, p.y)], 1u);
        }
        __syncthreads();
        if (tid == 0) {                            // tiny exclusive scan of 4
            unsigned a0 = qoff[0], a1 = qoff[1], a2 = qoff[2];
            qoff[0] = 0; qoff[1] = a0; qoff[2] = a0 + a1; qoff[3] = a0 + a1 + a2;
        }
        __syncthreads();
        // scatter order indices (quadrant-sorted)
        for (int i = tid; i < m; i += 512) {
            fx2 p = sxy[i];
            unsigned r = atomicAdd(&qoff[quad_of(p.x, p.y)], 1u);
            sord[r] = (unsigned short)i;
        }
        __syncthreads();
        // process quadrant-ordered: 8 lanes per point, unroll-2
        int i = tid >> 3;
        for (; i + 64 < m; i += 128) {
            int j0 = sord[i], j1 = sord[i + 64];
            fx2 pa = sxy[j0]; unsigned na = snn[j0];
            fx2 pb = sxy[j1]; unsigned nb = snn[j1];
            fx4 oa = bilerp_one(g, res, pa.x, pa.y);
            fx4 ob = bilerp_one(g, res, pb.x, pb.y);
            ((fx4*)out)[(size_t)na * 8 + lod] = oa;   // full-line merge in L2
            ((fx4*)out)[(size_t)nb * 8 + lod] = ob;
        }
        for (; i < m; i += 64) {
            int j = sord[i];
            fx2 p = sxy[j]; unsigned n = snn[j];
            fx4 o = bilerp_one(g, res, p.x, p.y);
            ((fx4*)out)[(size_t)n * 8 + lod] = o;
        }
        __syncthreads();                           // before next chunk reuse
    }
}

// ---- Fallback: proven round-2 monolithic kernel -----------------------------
__global__ __launch_bounds__(256) void densegrid_kernel(
    const float* __restrict__ xin,
    const float* __restrict__ g0, const float* __restrict__ g1,
    const float* __restrict__ g2, const float* __restrict__ g3,
    const float* __restrict__ g4, const float* __restrict__ g5,
    const float* __restrict__ g6, const float* __restrict__ g7,
    float* __restrict__ out, int npts) {
    int tid = blockIdx.x * blockDim.x + threadIdx.x;
    int n = tid >> 3;
    if (n >= npts) return;
    int lod = tid & 7;
    const float* g =
        (lod < 4) ? ((lod < 2) ? ((lod == 0) ? g0 : g1)
                               : ((lod == 2) ? g2 : g3))
                  : ((lod < 6) ? ((lod == 4) ? g4 : g5)
                               : ((lod == 6) ? g6 : g7));
    int res = 16 << lod;
    fx2 p = *(const fx2*)(xin + (size_t)n * 2);
    fx4 o = bilerp_one(g, res, p.x, p.y);
    __builtin_nontemporal_store(o, (fx4*)out + (size_t)n * 8 + lod);
}

extern "C" void kernel_launch(void* const* d_in, const int* in_sizes, int n_in,
                              void* d_out, int out_size, void* d_ws, size_t ws_size,
                              hipStream_t stream) {
    const float* x  = (const float*)d_in[0];
    const float* g0 = (const float*)d_in[1];
    const float* g1 = (const float*)d_in[2];
    const float* g2 = (const float*)d_in[3];
    const float* g3 = (const float*)d_in[4];
    const float* g4 = (const float*)d_in[5];
    const float* g5 = (const float*)d_in[6];
    const float* g6 = (const float*)d_in[7];
    const float* g7 = (const float*)d_in[8];
    float* out = (float*)d_out;
    int npts = in_sizes[0] / 2;

    int nblk = (npts + PPB - 1) / PPB;            // 245 for 2M points
    size_t mat  = (((size_t)NBINS * nblk * 4) + 255) & ~(size_t)255;
    size_t o_T  = mat;
    size_t o_bs = o_T + (((size_t)NBINS * 4 + 255) & ~(size_t)255);
    size_t o_xy = o_bs + ((((size_t)NBINS + 1) * 4 + 255) & ~(size_t)255);
    size_t o_n  = o_xy + (size_t)npts * 8;
    size_t need = o_n + (size_t)npts * 4;         // ~28.05 MB @ 2M pts

    if (ws_size >= need) {
        unsigned* cnt      = (unsigned*)d_ws;     // becomes offs after rowscan
        unsigned* T        = (unsigned*)((char*)d_ws + o_T);
        unsigned* binStart = (unsigned*)((char*)d_ws + o_bs);
        fx2*      recXY    = (fx2*)((char*)d_ws + o_xy);
        unsigned* recN     = (unsigned*)((char*)d_ws + o_n);

        hist2_kernel<<<nblk, 1024, 0, stream>>>(x, cnt, npts, nblk);
        rowsum_kernel<<<(NBINS * 64) / 256, 256, 0, stream>>>(cnt, T, nblk);
        scanT_kernel<<<1, 1024, 0, stream>>>(T, binStart, npts);
        rowscan_kernel<<<(NBINS * 64) / 256, 256, 0, stream>>>(cnt, binStart, nblk);
        scatter2_kernel<<<nblk, 1024, 0, stream>>>(x, cnt, recXY, recN, npts, nblk);
        binned_kernel<<<NBINS, 512, 0, stream>>>(recXY, recN, binStart,
                                                 g0, g1, g2, g3, g4, g5, g6, g7,
                                                 out);
    } else {
        int total = npts * 8;
        densegrid_kernel<<<(total + 255) / 256, 256, 0, stream>>>(
            x, g0, g1, g2, g3, g4, g5, g6, g7, out, npts);
    }
}

// Round 10
// 148.713 us; speedup vs baseline: 1.7189x; 1.5549x over previous
//
#include <hip/hip_runtime.h>

// DenseGrid multi-LOD bilinear — binned pipeline v8 (lod-per-wave).
// R2: monolithic 340us (L2-miss bound, FETCH 873MB).
// R4: bin-order + full-line writes: binned 167us.
// R6/R7: atomic-free counting sort, ~39us pre-pass; SoA recs FETCH 69.5MB.
// R8: 16384-bin experiment: binned 155 but sort 100us. R9: quadrant sub-sort
//     binned 159.5 / FETCH 57MB, but cached stores polluted LLC -> pre-pass
//     debt 39->71us. Binned is TCP-transaction bound (~14 line-accesses/pt
//     with mixed-lod waves: only 8 lanes share a LOD per instruction).
// R10: ONE LOD PER WAVE: stage 256-pt chunk in LDS, quadrant-sort, wave w
//      computes lod w for all pts (64 lanes same lod+quadrant -> low-lod
//      gathers collapse to 1-2 lines/instr; ~6 line-accesses/pt). Results via
//      LDS sres[256][9] (padded, conflict-free), store phase remaps to
//      8-lanes-per-point NT full-line stores (no LLC pollution).

typedef float    fx4 __attribute__((ext_vector_type(4)));
typedef float    fx2 __attribute__((ext_vector_type(2)));
typedef unsigned ux4 __attribute__((ext_vector_type(4)));

#define NBDIM 64
#define NBINS (NBDIM * NBDIM)
#define PPB   8192              // points per sort block
#define CHUNK 256               // points per binned chunk

__device__ __forceinline__ int bin_of(float px, float py) {
    int bx = min(max((int)(px * (float)NBDIM), 0), NBDIM - 1);
    int by = min(max((int)(py * (float)NBDIM), 0), NBDIM - 1);
    return by * NBDIM + bx;
}

__device__ __forceinline__ int quad_of(float px, float py) {
    int qx = min(max((int)(px * 128.0f), 0), 127) & 1;
    int qy = min(max((int)(py * 128.0f), 0), 127) & 1;
    return qy * 2 + qx;
}

__device__ __forceinline__ fx4 bilerp_one(const float* __restrict__ g, int res,
                                          float px, float py) {
    float rm1 = (float)(res - 1);
    float fx = px * rm1, fy = py * rm1;
    float cmax = rm1 - 1e-5f;
    float xc = fminf(fmaxf(fx, 0.0f), cmax);
    float yc = fminf(fmaxf(fy, 0.0f), cmax);
    int x1 = (int)xc, y1 = (int)yc;              // >=0 -> trunc == floor
    int x2 = min(x1 + 1, res - 1), y2 = min(y1 + 1, res - 1);
    float x1f = (float)x1, y1f = (float)y1, x2f = (float)x2, y2f = (float)y2;
    float w1 = (x2f - fx) * (y2f - fy);
    float w2 = (fx - x1f) * (y2f - fy);
    float w3 = (x2f - fx) * (fy - y1f);
    float w4 = (fx - x1f) * (fy - y1f);
    const fx4* gc = (const fx4*)g;
    fx4 v1 = gc[x1 + y1 * res];
    fx4 v2 = gc[x2 + y1 * res];
    fx4 v3 = gc[x1 + y2 * res];
    fx4 v4 = gc[x2 + y2 * res];
    return w1 * v1 + w2 * v2 + w3 * v3 + w4 * v4;
}

// ---- P1: per-block LDS histogram -> cnt[bin*nblk + blk] ---------------------
__global__ __launch_bounds__(1024) void hist2_kernel(const float* __restrict__ x,
                                                     unsigned* __restrict__ cnt,
                                                     int npts, int nblk) {
    __shared__ unsigned h[NBINS];                 // 16 KB
    int t = threadIdx.x, blk = blockIdx.x;
    for (int i = t; i < NBINS; i += 1024) h[i] = 0;
    __syncthreads();
    size_t base = (size_t)blk * PPB;
    #pragma unroll
    for (int j = 0; j < 4; ++j) {
        size_t n = base + (size_t)j * 2048 + (size_t)t * 2;  // 2 pts/thread/iter
        if (n < (size_t)npts) {
            if (n + 1 < (size_t)npts) {
                fx4 q = *(const fx4*)(x + 2 * n);
                atomicAdd(&h[bin_of(q.x, q.y)], 1u);
                atomicAdd(&h[bin_of(q.z, q.w)], 1u);
            } else {
                fx2 q = *(const fx2*)(x + 2 * n);
                atomicAdd(&h[bin_of(q.x, q.y)], 1u);
            }
        }
    }
    __syncthreads();
    for (int i = t; i < NBINS; i += 1024)
        cnt[(size_t)i * nblk + blk] = h[i];
}

// ---- P2: per-bin totals (one wave per bin row) ------------------------------
__global__ __launch_bounds__(256) void rowsum_kernel(const unsigned* __restrict__ cnt,
                                                     unsigned* __restrict__ T,
                                                     int nblk) {
    int wave = (blockIdx.x * 256 + threadIdx.x) >> 6;
    int lane = threadIdx.x & 63;
    if (wave >= NBINS) return;
    const unsigned* row = cnt + (size_t)wave * nblk;
    unsigned sum = 0;
    for (int c = lane; c < nblk; c += 64) sum += row[c];
    #pragma unroll
    for (int d = 32; d; d >>= 1) sum += __shfl_down(sum, d, 64);
    if (lane == 0) T[wave] = sum;
}

// ---- P3: exclusive scan of 4096 bin totals (single block) -------------------
__global__ __launch_bounds__(1024) void scanT_kernel(const unsigned* __restrict__ T,
                                                     unsigned* __restrict__ binStart,
                                                     int npts) {
    __shared__ unsigned s[1024];
    int t = threadIdx.x;
    ux4 h = ((const ux4*)T)[t];
    unsigned seg = h.x + h.y + h.z + h.w;
    s[t] = seg;
    __syncthreads();
    for (int off = 1; off < 1024; off <<= 1) {    // Hillis-Steele inclusive
        unsigned v = (t >= off) ? s[t - off] : 0u;
        __syncthreads();
        s[t] += v;
        __syncthreads();
    }
    unsigned run = t ? s[t - 1] : 0u;
    binStart[4 * t + 0] = run; run += h.x;
    binStart[4 * t + 1] = run; run += h.y;
    binStart[4 * t + 2] = run; run += h.z;
    binStart[4 * t + 3] = run;
    if (t == 1023) binStart[NBINS] = (unsigned)npts;
}

// ---- P4: per-bin row exclusive scan, IN PLACE (cnt becomes abs offsets) -----
__global__ __launch_bounds__(256) void rowscan_kernel(unsigned* __restrict__ cnt,
                                                      const unsigned* __restrict__ binStart,
                                                      int nblk) {
    int wave = (blockIdx.x * 256 + threadIdx.x) >> 6;
    int lane = threadIdx.x & 63;
    if (wave >= NBINS) return;
    unsigned* row = cnt + (size_t)wave * nblk;
    unsigned running = binStart[wave];
    for (int c0 = 0; c0 < nblk; c0 += 64) {
        int c = c0 + lane;
        unsigned v = (c < nblk) ? row[c] : 0u;
        unsigned orig = v;
        #pragma unroll
        for (int d = 1; d < 64; d <<= 1) {
            unsigned y = __shfl_up(v, d, 64);
            if (lane >= d) v += y;
        }
        if (c < nblk) row[c] = running + v - orig;    // exclusive + base
        running += __shfl(v, 63, 64);
    }
}

// ---- P5: scatter SoA records (LDS-local ranks, no global atomics) -----------
__global__ __launch_bounds__(1024) void scatter2_kernel(const float* __restrict__ x,
                                                        const unsigned* __restrict__ offs,
                                                        fx2* __restrict__ recXY,
                                                        unsigned* __restrict__ recN,
                                                        int npts, int nblk) {
    __shared__ unsigned off[NBINS];               // 16 KB
    int t = threadIdx.x, blk = blockIdx.x;
    for (int i = t; i < NBINS; i += 1024)
        off[i] = offs[(size_t)i * nblk + blk];
    __syncthreads();
    size_t base = (size_t)blk * PPB;
    #pragma unroll
    for (int j = 0; j < 4; ++j) {
        size_t n = base + (size_t)j * 2048 + (size_t)t * 2;
        if (n < (size_t)npts) {
            if (n + 1 < (size_t)npts) {
                fx4 q = *(const fx4*)(x + 2 * n);
                unsigned s0 = atomicAdd(&off[bin_of(q.x, q.y)], 1u);
                unsigned s1 = atomicAdd(&off[bin_of(q.z, q.w)], 1u);
                fx2 a; a.x = q.x; a.y = q.y;
                fx2 b2; b2.x = q.z; b2.y = q.w;
                recXY[s0] = a;  recN[s0] = (unsigned)n;
                recXY[s1] = b2; recN[s1] = (unsigned)(n + 1);
            } else {
                fx2 q = *(const fx2*)(x + 2 * n);
                unsigned s0 = atomicAdd(&off[bin_of(q.x, q.y)], 1u);
                recXY[s0] = q; recN[s0] = (unsigned)n;
            }
        }
    }
}

// ---- P6: binned main pass — lod-per-wave, LDS result buffer, NT stores ------
__global__ __launch_bounds__(512) void binned_kernel(
    const fx2* __restrict__ recXY, const unsigned* __restrict__ recN,
    const unsigned* __restrict__ binStart,
    const float* __restrict__ g0, const float* __restrict__ g1,
    const float* __restrict__ g2, const float* __restrict__ g3,
    const float* __restrict__ g4, const float* __restrict__ g5,
    const float* __restrict__ g6, const float* __restrict__ g7,
    float* __restrict__ out) {
    __shared__ fx4 sres[CHUNK * 9];               // 36 KB, +1 pad: bank-safe
    __shared__ fx2 sxy[CHUNK];                    // 2 KB
    __shared__ unsigned snn[CHUNK];               // 1 KB
    __shared__ unsigned short sord[CHUNK];        // 0.5 KB
    __shared__ unsigned qoff[4];
    // total ~39.6 KB -> 4 blocks/CU = 32 waves (full occupancy)

    // XCD swizzle: 4096 bins % 8 == 0 -> each XCD gets 512 consecutive bins.
    int b = (blockIdx.x & 7) * (NBINS / 8) + (blockIdx.x >> 3);
    unsigned s = binStart[b], e = binStart[b + 1];
    int tid = threadIdx.x;
    int wv  = tid >> 6;                            // 0..7 = this wave's LOD
    int lane = tid & 63;
    const float* g =
        (wv < 4) ? ((wv < 2) ? ((wv == 0) ? g0 : g1)
                             : ((wv == 2) ? g2 : g3))
                 : ((wv < 6) ? ((wv == 4) ? g4 : g5)
                             : ((wv == 6) ? g6 : g7));
    int res = 16 << wv;

    for (unsigned c0 = s; c0 < e; c0 += CHUNK) {
        int m = (int)min((unsigned)CHUNK, e - c0);
        // coalesced stage of records
        for (int i = tid; i < m; i += 512) {
            sxy[i] = recXY[c0 + i];
            snn[i] = recN[c0 + i];
        }
        if (tid < 4) qoff[tid] = 0;
        __syncthreads();
        // quadrant counting sort (order indices only)
        for (int i = tid; i < m; i += 512) {
            fx2 p = sxy[i];
            atomicAdd(&qoff[quad_of(p.x, p.y)], 1u);
        }
        __syncthreads();
        if (tid == 0) {
            unsigned a0 = qoff[0], a1 = qoff[1], a2 = qoff[2];
            qoff[0] = 0; qoff[1] = a0; qoff[2] = a0 + a1; qoff[3] = a0 + a1 + a2;
        }
        __syncthreads();
        for (int i = tid; i < m; i += 512) {
            fx2 p = sxy[i];
            unsigned r = atomicAdd(&qoff[quad_of(p.x, p.y)], 1u);
            sord[r] = (unsigned short)i;
        }
        __syncthreads();
        // compute phase: wave wv does LOD wv for all m points (quadrant order)
        for (int i = lane; i < m; i += 64) {
            int j = sord[i];
            fx2 p = sxy[j];
            sres[j * 9 + wv] = bilerp_one(g, res, p.x, p.y);
        }
        __syncthreads();
        // store phase: 8 lanes per point -> one NT full 128B line
        for (int k = tid; k < m * 8; k += 512) {
            int p = k >> 3, l = k & 7;
            fx4 v = sres[p * 9 + l];
            unsigned n = snn[p];
            __builtin_nontemporal_store(v, (fx4*)out + (size_t)n * 8 + l);
        }
        __syncthreads();                           // before next chunk reuse
    }
}

// ---- Fallback: proven round-2 monolithic kernel -----------------------------
__global__ __launch_bounds__(256) void densegrid_kernel(
    const float* __restrict__ xin,
    const float* __restrict__ g0, const float* __restrict__ g1,
    const float* __restrict__ g2, const float* __restrict__ g3,
    const float* __restrict__ g4, const float* __restrict__ g5,
    const float* __restrict__ g6, const float* __restrict__ g7,
    float* __restrict__ out, int npts) {
    int tid = blockIdx.x * blockDim.x + threadIdx.x;
    int n = tid >> 3;
    if (n >= npts) return;
    int lod = tid & 7;
    const float* g =
        (lod < 4) ? ((lod < 2) ? ((lod == 0) ? g0 : g1)
                               : ((lod == 2) ? g2 : g3))
                  : ((lod < 6) ? ((lod == 4) ? g4 : g5)
                               : ((lod == 6) ? g6 : g7));
    int res = 16 << lod;
    fx2 p = *(const fx2*)(xin + (size_t)n * 2);
    fx4 o = bilerp_one(g, res, p.x, p.y);
    __builtin_nontemporal_store(o, (fx4*)out + (size_t)n * 8 + lod);
}

extern "C" void kernel_launch(void* const* d_in, const int* in_sizes, int n_in,
                              void* d_out, int out_size, void* d_ws, size_t ws_size,
                              hipStream_t stream) {
    const float* x  = (const float*)d_in[0];
    const float* g0 = (const float*)d_in[1];
    const float* g1 = (const float*)d_in[2];
    const float* g2 = (const float*)d_in[3];
    const float* g3 = (const float*)d_in[4];
    const float* g4 = (const float*)d_in[5];
    const float* g5 = (const float*)d_in[6];
    const float* g6 = (const float*)d_in[7];
    const float* g7 = (const float*)d_in[8];
    float* out = (float*)d_out;
    int npts = in_sizes[0] / 2;

    int nblk = (npts + PPB - 1) / PPB;            // 245 for 2M points
    size_t mat  = (((size_t)NBINS * nblk * 4) + 255) & ~(size_t)255;
    size_t o_T  = mat;
    size_t o_bs = o_T + (((size_t)NBINS * 4 + 255) & ~(size_t)255);
    size_t o_xy = o_bs + ((((size_t)NBINS + 1) * 4 + 255) & ~(size_t)255);
    size_t o_n  = o_xy + (size_t)npts * 8;
    size_t need = o_n + (size_t)npts * 4;         // ~28.05 MB @ 2M pts

    if (ws_size >= need) {
        unsigned* cnt      = (unsigned*)d_ws;     // becomes offs after rowscan
        unsigned* T        = (unsigned*)((char*)d_ws + o_T);
        unsigned* binStart = (unsigned*)((char*)d_ws + o_bs);
        fx2*      recXY    = (fx2*)((char*)d_ws + o_xy);
        unsigned* recN     = (unsigned*)((char*)d_ws + o_n);

        hist2_kernel<<<nblk, 1024, 0, stream>>>(x, cnt, npts, nblk);
        rowsum_kernel<<<(NBINS * 64) / 256, 256, 0, stream>>>(cnt, T, nblk);
        scanT_kernel<<<1, 1024, 0, stream>>>(T, binStart, npts);
        rowscan_kernel<<<(NBINS * 64) / 256, 256, 0, stream>>>(cnt, binStart, nblk);
        scatter2_kernel<<<nblk, 1024, 0, stream>>>(x, cnt, recXY, recN, npts, nblk);
        binned_kernel<<<NBINS, 512, 0, stream>>>(recXY, recN, binStart,
                                                 g0, g1, g2, g3, g4, g5, g6, g7,
                                                 out);
    } else {
        int total = npts * 8;
        densegrid_kernel<<<(total + 255) / 256, 256, 0, stream>>>(
            x, g0, g1, g2, g3, g4, g5, g6, g7, out, npts);
    }
}